// Round 2
// baseline (688.891 us; speedup 1.0000x reference)
//
#include <hip/hip_runtime.h>
#include <hip/hip_bf16.h>
#include <math.h>

// Problem constants (match reference)
#define T_TOK 1024
#define H_DIM 1024
#define I_DIM 512
#define E_NUM 32
#define K_TOP 4
#define G_NUM 8
#define TG_NUM 4
#define CAP 256              // C = 2*T*K/E
#define IS_DIM 1024          // I * NS
#define RSCALE 2.5f

// ws layout (byte offsets)
//   0      : int   cnt[E]
//   1024   : int   eidx[T*K]          (16 KB)  flat (t,k) expert ids
//   17408  : float wnorm[T*K]         (16 KB)  flat normalized weights (*2.5)
//   33792  : int   slot_token[E*CAP]  (32 KB)
//   66560  : float slot_w[E*CAP]      (32 KB)
//   99328  : float act[E*CAP*I]       (16 MB)
//   +16MB  : float acts_shared[T*IS]  (4 MB)
#define WS_EIDX_OFF   1024
#define WS_WN_OFF     17408
#define WS_STOK_OFF   33792
#define WS_SW_OFF     66560
#define WS_ACT_OFF    99328
#define WS_ACTS_OFF   (99328 + (size_t)E_NUM*CAP*I_DIM*4)

// -------- gating: logits -> sigmoid -> group-limited top-k (per token) --------
__global__ __launch_bounds__(256) void gate_kernel(
    const float* __restrict__ x, const float* __restrict__ gate_w,
    const float* __restrict__ e_bias,
    int* __restrict__ eidx, float* __restrict__ wnorm)
{
    __shared__ float xs[H_DIM];
    __shared__ float logits[E_NUM];
    const int t = blockIdx.x;
    const int tid = threadIdx.x;
    ((float4*)xs)[tid] = ((const float4*)(x + (size_t)t * H_DIM))[tid];
    __syncthreads();

    const int e = tid >> 3, sub = tid & 7;   // 32 experts x 8 threads
    const float* gw = gate_w + (size_t)e * H_DIM + sub * 128;
    const float* xr = xs + sub * 128;
    float p = 0.f;
    #pragma unroll 8
    for (int h = 0; h < 128; ++h) p += xr[h] * gw[h];
    for (int off = 4; off; off >>= 1) p += __shfl_down(p, off, 8);
    if (sub == 0) logits[e] = p;
    __syncthreads();
    if (tid != 0) return;

    float sc[E_NUM], sfc[E_NUM];
    for (int i = 0; i < E_NUM; ++i) {
        sc[i] = 1.f / (1.f + expf(-logits[i]));
        sfc[i] = sc[i] + e_bias[i];
    }
    // per-group top-2 sum (groups of E/G = 4)
    float gs[G_NUM];
    for (int g = 0; g < G_NUM; ++g) {
        float m1 = -1e30f, m2 = -1e30f;
        for (int j = 0; j < E_NUM / G_NUM; ++j) {
            float v = sfc[g * (E_NUM / G_NUM) + j];
            if (v > m1) { m2 = m1; m1 = v; } else if (v > m2) m2 = v;
        }
        gs[g] = m1 + m2;
    }
    // keep top TG groups (first-occurrence on ties, matches lax.top_k)
    bool gm[G_NUM];
    for (int g = 0; g < G_NUM; ++g) gm[g] = false;
    for (int it = 0; it < TG_NUM; ++it) {
        int best = -1; float bv = -1e30f;
        for (int g = 0; g < G_NUM; ++g) if (!gm[g] && gs[g] > bv) { bv = gs[g]; best = g; }
        gm[best] = true;
    }
    float sm[E_NUM];
    for (int i = 0; i < E_NUM; ++i) sm[i] = gm[i / (E_NUM / G_NUM)] ? sfc[i] : 0.0f;
    // top-K experts (rank order preserved); weights from RAW scores
    int idx[K_TOP]; float w[K_TOP]; float tsum = 0.f;
    for (int it = 0; it < K_TOP; ++it) {
        int best = 0; float bv = -1e30f;
        for (int i = 0; i < E_NUM; ++i) if (sm[i] > bv) { bv = sm[i]; best = i; }
        sm[best] = -1e30f;
        idx[it] = best; w[it] = sc[best]; tsum += w[it];
    }
    float inv = RSCALE / (tsum + 1e-20f);
    const int base = t * K_TOP;
    for (int it = 0; it < K_TOP; ++it) {
        eidx[base + it] = idx[it];
        wnorm[base + it] = w[it] * inv;
    }
}

// -------- deterministic capacity dispatch: replicates reference cumsum order ----
// one block, 256 threads = 32 experts x 8 segments of 512 flat entries
__global__ __launch_bounds__(256) void assign_kernel(
    const int* __restrict__ eidx, const float* __restrict__ wnorm,
    int* __restrict__ cnt, int* __restrict__ slot_token, float* __restrict__ slot_w)
{
    __shared__ int   se[T_TOK * K_TOP];
    __shared__ float swt[T_TOK * K_TOP];
    const int tid = threadIdx.x;
    for (int i = tid; i < T_TOK * K_TOP; i += 256) { se[i] = eidx[i]; swt[i] = wnorm[i]; }
    __syncthreads();

    const int e = tid >> 3;       // expert 0..31
    const int seg = tid & 7;      // segment 0..7
    const int base = seg * 512;
    int c = 0;
    for (int i = 0; i < 512; ++i) c += (se[base + i] == e);
    int excl = 0, total = 0;
    for (int s = 0; s < 8; ++s) {
        int cs = __shfl(c, s, 8);
        total += cs;
        if (s < seg) excl += cs;
    }
    if (seg == 0) cnt[e] = total;
    int pos = excl;
    for (int i = 0; i < 512; ++i) {
        if (se[base + i] == e) {
            if (pos < CAP) {
                slot_token[e * CAP + pos] = (base + i) >> 2;   // flat/K = token
                slot_w[e * CAP + pos] = swt[base + i];
            }
            ++pos;
        }
    }
}

// -------- classic 64x64 fp32 tile bodies --------
#define FMA16() do {                                                     \
    acc[0][0] += a.x*b.x; acc[0][1] += a.x*b.y; acc[0][2] += a.x*b.z; acc[0][3] += a.x*b.w; \
    acc[1][0] += a.y*b.x; acc[1][1] += a.y*b.y; acc[1][2] += a.y*b.z; acc[1][3] += a.y*b.w; \
    acc[2][0] += a.z*b.x; acc[2][1] += a.z*b.y; acc[2][2] += a.z*b.z; acc[2][3] += a.z*b.w; \
    acc[3][0] += a.w*b.x; acc[3][1] += a.w*b.y; acc[3][2] += a.w*b.z; acc[3][3] += a.w*b.w; \
} while (0)

__device__ __forceinline__ float silu_(float g) { return g / (1.f + expf(-g)); }

// routed gate_up + SiLU*mul, tw folded in.  grid (I/32, CAP/64, E)
__global__ __launch_bounds__(256) void moe_gu_kernel(
    const float* __restrict__ x, const float* __restrict__ w_gate_up,
    const int* __restrict__ cnt, const int* __restrict__ slot_token,
    const float* __restrict__ slot_w, float* __restrict__ act)
{
    const int e = blockIdx.z;
    const int ne = min(cnt[e], CAP);
    const int r0 = blockIdx.y * 64;
    if (r0 >= ne) return;
    const int n0 = blockIdx.x * 32;

    __shared__ __align__(16) float As[16][68];
    __shared__ __align__(16) float Bs[16][68];
    __shared__ int toks[64];
    const int tid = threadIdx.x;
    if (tid < 64) {
        int p = r0 + tid;
        toks[tid] = (p < ne) ? slot_token[e * CAP + p] : -1;
    }
    __syncthreads();

    const int lr = tid >> 2;            // 0..63
    const int lk = (tid & 3) << 2;      // 0,4,8,12
    // interleaved effective column: even -> gate(n0 + lr/2), odd -> up(I + n0 + lr/2)
    const int wr = (lr & 1) ? (I_DIM + n0 + (lr >> 1)) : (n0 + (lr >> 1));
    const float* bptr = w_gate_up + (size_t)e * (2 * I_DIM) * H_DIM + (size_t)wr * H_DIM + lk;
    const int mytok = toks[lr];
    const float* aptr = (mytok >= 0) ? (x + (size_t)mytok * H_DIM + lk) : nullptr;

    const int trow = tid >> 4, tcol = tid & 15;
    float acc[4][4] = {};

    for (int k0 = 0; k0 < H_DIM; k0 += 16) {
        float4 av = make_float4(0.f, 0.f, 0.f, 0.f);
        if (aptr) av = *(const float4*)(aptr + k0);
        float4 bv = *(const float4*)(bptr + k0);
        As[lk + 0][lr] = av.x; As[lk + 1][lr] = av.y; As[lk + 2][lr] = av.z; As[lk + 3][lr] = av.w;
        Bs[lk + 0][lr] = bv.x; Bs[lk + 1][lr] = bv.y; Bs[lk + 2][lr] = bv.z; Bs[lk + 3][lr] = bv.w;
        __syncthreads();
        #pragma unroll
        for (int kk = 0; kk < 16; ++kk) {
            float4 a = *(const float4*)&As[kk][trow << 2];
            float4 b = *(const float4*)&Bs[kk][tcol << 2];
            FMA16();
        }
        __syncthreads();
    }

    const int c0 = n0 + 2 * tcol;
    #pragma unroll
    for (int i = 0; i < 4; ++i) {
        int p = r0 + (trow << 2) + i;
        if (p < ne) {
            float s = slot_w[e * CAP + p];
            float a0 = s * silu_(acc[i][0]) * acc[i][1];
            float a1 = s * silu_(acc[i][2]) * acc[i][3];
            float* arow = act + ((size_t)e * CAP + p) * I_DIM;
            arow[c0] = a0; arow[c0 + 1] = a1;
        }
    }
}

// routed down + scatter-add.  grid (H/64, CAP/64, E)
__global__ __launch_bounds__(256) void moe_down_kernel(
    const float* __restrict__ act, const float* __restrict__ w_down,
    const int* __restrict__ cnt, const int* __restrict__ slot_token,
    float* __restrict__ out)
{
    const int e = blockIdx.z;
    const int ne = min(cnt[e], CAP);
    const int r0 = blockIdx.y * 64;
    if (r0 >= ne) return;
    const int h0 = blockIdx.x * 64;

    __shared__ __align__(16) float As[16][68];
    __shared__ __align__(16) float Bs[16][68];
    const int tid = threadIdx.x;
    const int lr = tid >> 2;
    const int lk = (tid & 3) << 2;
    const bool avalid = (r0 + lr) < ne;
    const float* aptr = act + ((size_t)e * CAP + (r0 + lr)) * I_DIM + lk;
    const float* bptr = w_down + ((size_t)e * H_DIM + (h0 + lr)) * I_DIM + lk;
    const int trow = tid >> 4, tcol = tid & 15;
    float acc[4][4] = {};

    for (int k0 = 0; k0 < I_DIM; k0 += 16) {
        float4 av = make_float4(0.f, 0.f, 0.f, 0.f);
        if (avalid) av = *(const float4*)(aptr + k0);
        float4 bv = *(const float4*)(bptr + k0);
        As[lk + 0][lr] = av.x; As[lk + 1][lr] = av.y; As[lk + 2][lr] = av.z; As[lk + 3][lr] = av.w;
        Bs[lk + 0][lr] = bv.x; Bs[lk + 1][lr] = bv.y; Bs[lk + 2][lr] = bv.z; Bs[lk + 3][lr] = bv.w;
        __syncthreads();
        #pragma unroll
        for (int kk = 0; kk < 16; ++kk) {
            float4 a = *(const float4*)&As[kk][trow << 2];
            float4 b = *(const float4*)&Bs[kk][tcol << 2];
            FMA16();
        }
        __syncthreads();
    }

    #pragma unroll
    for (int i = 0; i < 4; ++i) {
        int p = r0 + (trow << 2) + i;
        if (p < ne) {
            int tt = slot_token[e * CAP + p];
            float* orow = out + (size_t)tt * H_DIM + h0 + (tcol << 2);
            atomicAdd(&orow[0], acc[i][0]);
            atomicAdd(&orow[1], acc[i][1]);
            atomicAdd(&orow[2], acc[i][2]);
            atomicAdd(&orow[3], acc[i][3]);
        }
    }
}

// shared-expert gate_up + SiLU*mul.  grid (IS/32, T/64)
__global__ __launch_bounds__(256) void shared_gu_kernel(
    const float* __restrict__ x, const float* __restrict__ w_gus,
    float* __restrict__ acts)
{
    const int t0 = blockIdx.y * 64;
    const int n0 = blockIdx.x * 32;
    __shared__ __align__(16) float As[16][68];
    __shared__ __align__(16) float Bs[16][68];
    const int tid = threadIdx.x;
    const int lr = tid >> 2;
    const int lk = (tid & 3) << 2;
    const int wr = (lr & 1) ? (IS_DIM + n0 + (lr >> 1)) : (n0 + (lr >> 1));
    const float* aptr = x + (size_t)(t0 + lr) * H_DIM + lk;
    const float* bptr = w_gus + (size_t)wr * H_DIM + lk;
    const int trow = tid >> 4, tcol = tid & 15;
    float acc[4][4] = {};

    for (int k0 = 0; k0 < H_DIM; k0 += 16) {
        float4 av = *(const float4*)(aptr + k0);
        float4 bv = *(const float4*)(bptr + k0);
        As[lk + 0][lr] = av.x; As[lk + 1][lr] = av.y; As[lk + 2][lr] = av.z; As[lk + 3][lr] = av.w;
        Bs[lk + 0][lr] = bv.x; Bs[lk + 1][lr] = bv.y; Bs[lk + 2][lr] = bv.z; Bs[lk + 3][lr] = bv.w;
        __syncthreads();
        #pragma unroll
        for (int kk = 0; kk < 16; ++kk) {
            float4 a = *(const float4*)&As[kk][trow << 2];
            float4 b = *(const float4*)&Bs[kk][tcol << 2];
            FMA16();
        }
        __syncthreads();
    }

    const int c0 = n0 + 2 * tcol;
    #pragma unroll
    for (int i = 0; i < 4; ++i) {
        int t = t0 + (trow << 2) + i;
        float* arow = acts + (size_t)t * IS_DIM;
        arow[c0]     = silu_(acc[i][0]) * acc[i][1];
        arow[c0 + 1] = silu_(acc[i][2]) * acc[i][3];
    }
}

// shared-expert down, plain write (initializes out).  grid (H/64, T/64)
__global__ __launch_bounds__(256) void shared_down_kernel(
    const float* __restrict__ acts, const float* __restrict__ w_ds,
    float* __restrict__ out)
{
    const int t0 = blockIdx.y * 64;
    const int h0 = blockIdx.x * 64;
    __shared__ __align__(16) float As[16][68];
    __shared__ __align__(16) float Bs[16][68];
    const int tid = threadIdx.x;
    const int lr = tid >> 2;
    const int lk = (tid & 3) << 2;
    const float* aptr = acts + (size_t)(t0 + lr) * IS_DIM + lk;
    const float* bptr = w_ds + (size_t)(h0 + lr) * IS_DIM + lk;
    const int trow = tid >> 4, tcol = tid & 15;
    float acc[4][4] = {};

    for (int k0 = 0; k0 < IS_DIM; k0 += 16) {
        float4 av = *(const float4*)(aptr + k0);
        float4 bv = *(const float4*)(bptr + k0);
        As[lk + 0][lr] = av.x; As[lk + 1][lr] = av.y; As[lk + 2][lr] = av.z; As[lk + 3][lr] = av.w;
        Bs[lk + 0][lr] = bv.x; Bs[lk + 1][lr] = bv.y; Bs[lk + 2][lr] = bv.z; Bs[lk + 3][lr] = bv.w;
        __syncthreads();
        #pragma unroll
        for (int kk = 0; kk < 16; ++kk) {
            float4 a = *(const float4*)&As[kk][trow << 2];
            float4 b = *(const float4*)&Bs[kk][tcol << 2];
            FMA16();
        }
        __syncthreads();
    }

    #pragma unroll
    for (int i = 0; i < 4; ++i) {
        int t = t0 + (trow << 2) + i;
        float4 v = make_float4(acc[i][0], acc[i][1], acc[i][2], acc[i][3]);
        *(float4*)(out + (size_t)t * H_DIM + h0 + (tcol << 2)) = v;
    }
}

extern "C" void kernel_launch(void* const* d_in, const int* in_sizes, int n_in,
                              void* d_out, int out_size, void* d_ws, size_t ws_size,
                              hipStream_t stream) {
    const float* x   = (const float*)d_in[0];
    const float* gw  = (const float*)d_in[1];
    const float* eb  = (const float*)d_in[2];
    const float* wgu = (const float*)d_in[3];
    const float* wd  = (const float*)d_in[4];
    const float* wgs = (const float*)d_in[5];
    const float* wds = (const float*)d_in[6];
    float* out = (float*)d_out;
    char* ws = (char*)d_ws;

    int*   cnt   = (int*)(ws + 0);
    int*   eidx  = (int*)(ws + WS_EIDX_OFF);
    float* wnorm = (float*)(ws + WS_WN_OFF);
    int*   stok  = (int*)(ws + WS_STOK_OFF);
    float* sw    = (float*)(ws + WS_SW_OFF);
    float* act   = (float*)(ws + WS_ACT_OFF);
    float* acts  = (float*)(ws + WS_ACTS_OFF);

    gate_kernel<<<T_TOK, 256, 0, stream>>>(x, gw, eb, eidx, wnorm);
    assign_kernel<<<1, 256, 0, stream>>>(eidx, wnorm, cnt, stok, sw);
    shared_gu_kernel<<<dim3(IS_DIM / 32, T_TOK / 64), 256, 0, stream>>>(x, wgs, acts);
    shared_down_kernel<<<dim3(H_DIM / 64, T_TOK / 64), 256, 0, stream>>>(acts, wds, out);
    moe_gu_kernel<<<dim3(I_DIM / 32, CAP / 64, E_NUM), 256, 0, stream>>>(x, wgu, cnt, stok, sw, act);
    moe_down_kernel<<<dim3(H_DIM / 64, CAP / 64, E_NUM), 256, 0, stream>>>(act, wd, cnt, stok, out);
}

// Round 3
// 492.182 us; speedup vs baseline: 1.3997x; 1.3997x over previous
//
#include <hip/hip_runtime.h>
#include <hip/hip_bf16.h>
#include <math.h>

// Problem constants (match reference)
#define T_TOK 1024
#define H_DIM 1024
#define I_DIM 512
#define E_NUM 32
#define K_TOP 4
#define G_NUM 8
#define TG_NUM 4
#define CAP 256              // C = 2*T*K/E
#define IS_DIM 1024          // I * NS
#define RSCALE 2.5f

// ws layout (byte offsets)
//   0      : int   cnt[E]
//   1024   : int   eidx[T*K]
//   17408  : float wnorm[T*K]
//   33792  : int   slot_token[E*CAP]
//   66560  : float slot_w[E*CAP]
//   99328  : bf16  act[E*CAP*I]       (8 MB)
//   +8MB   : bf16  acts_shared[T*IS]  (2 MB)
#define WS_EIDX_OFF   1024
#define WS_WN_OFF     17408
#define WS_STOK_OFF   33792
#define WS_SW_OFF     66560
#define WS_ACT_OFF    99328
#define WS_ACTS_OFF   (99328 + (size_t)E_NUM*CAP*I_DIM*2)

typedef __attribute__((ext_vector_type(8))) short short8v;
typedef __attribute__((ext_vector_type(4))) short short4v;
typedef __attribute__((ext_vector_type(4))) float f32x4;

__device__ __forceinline__ short f2bf(float f) {
    unsigned u = __float_as_uint(f);
    u += 0x7FFFu + ((u >> 16) & 1u);
    return (short)(u >> 16);
}
__device__ __forceinline__ float silu_(float g) { return g / (1.f + expf(-g)); }

// LDS tile: 128 rows x 32 k (bf16), row stride 40 shorts (80 B, 16B-aligned)
#define LDSTRIDE 40

// -------- gating: logits -> sigmoid -> group-limited top-k (per token) --------
__global__ __launch_bounds__(256) void gate_kernel(
    const float* __restrict__ x, const float* __restrict__ gate_w,
    const float* __restrict__ e_bias,
    int* __restrict__ eidx, float* __restrict__ wnorm)
{
    __shared__ float xs[H_DIM];
    __shared__ float logits[E_NUM];
    const int t = blockIdx.x;
    const int tid = threadIdx.x;
    ((float4*)xs)[tid] = ((const float4*)(x + (size_t)t * H_DIM))[tid];
    __syncthreads();

    const int e = tid >> 3, sub = tid & 7;   // 32 experts x 8 threads
    const float* gw = gate_w + (size_t)e * H_DIM + sub * 128;
    const float* xr = xs + sub * 128;
    float p = 0.f;
    #pragma unroll 8
    for (int h = 0; h < 128; ++h) p += xr[h] * gw[h];
    for (int off = 4; off; off >>= 1) p += __shfl_down(p, off, 8);
    if (sub == 0) logits[e] = p;
    __syncthreads();
    if (tid != 0) return;

    float sc[E_NUM], sfc[E_NUM];
    for (int i = 0; i < E_NUM; ++i) {
        sc[i] = 1.f / (1.f + expf(-logits[i]));
        sfc[i] = sc[i] + e_bias[i];
    }
    float gs[G_NUM];
    for (int g = 0; g < G_NUM; ++g) {
        float m1 = -1e30f, m2 = -1e30f;
        for (int j = 0; j < E_NUM / G_NUM; ++j) {
            float v = sfc[g * (E_NUM / G_NUM) + j];
            if (v > m1) { m2 = m1; m1 = v; } else if (v > m2) m2 = v;
        }
        gs[g] = m1 + m2;
    }
    bool gm[G_NUM];
    for (int g = 0; g < G_NUM; ++g) gm[g] = false;
    for (int it = 0; it < TG_NUM; ++it) {
        int best = -1; float bv = -1e30f;
        for (int g = 0; g < G_NUM; ++g) if (!gm[g] && gs[g] > bv) { bv = gs[g]; best = g; }
        gm[best] = true;
    }
    float sm[E_NUM];
    for (int i = 0; i < E_NUM; ++i) sm[i] = gm[i / (E_NUM / G_NUM)] ? sfc[i] : 0.0f;
    int idx[K_TOP]; float w[K_TOP]; float tsum = 0.f;
    for (int it = 0; it < K_TOP; ++it) {
        int best = 0; float bv = -1e30f;
        for (int i = 0; i < E_NUM; ++i) if (sm[i] > bv) { bv = sm[i]; best = i; }
        sm[best] = -1e30f;
        idx[it] = best; w[it] = sc[best]; tsum += w[it];
    }
    float inv = RSCALE / (tsum + 1e-20f);
    const int base = t * K_TOP;
    for (int it = 0; it < K_TOP; ++it) {
        eidx[base + it] = idx[it];
        wnorm[base + it] = w[it] * inv;
    }
}

// -------- deterministic capacity dispatch (reference cumsum order) --------
__global__ __launch_bounds__(256) void assign_kernel(
    const int* __restrict__ eidx, const float* __restrict__ wnorm,
    int* __restrict__ cnt, int* __restrict__ slot_token, float* __restrict__ slot_w)
{
    __shared__ int   se[T_TOK * K_TOP];
    __shared__ float swt[T_TOK * K_TOP];
    const int tid = threadIdx.x;
    for (int i = tid; i < T_TOK * K_TOP; i += 256) { se[i] = eidx[i]; swt[i] = wnorm[i]; }
    __syncthreads();

    const int e = tid >> 3;
    const int seg = tid & 7;
    const int base = seg * 512;
    int c = 0;
    for (int i = 0; i < 512; ++i) c += (se[base + i] == e);
    int excl = 0, total = 0;
    for (int s = 0; s < 8; ++s) {
        int cs = __shfl(c, s, 8);
        total += cs;
        if (s < seg) excl += cs;
    }
    if (seg == 0) cnt[e] = total;
    int pos = excl;
    for (int i = 0; i < 512; ++i) {
        if (se[base + i] == e) {
            if (pos < CAP) {
                slot_token[e * CAP + pos] = (base + i) >> 2;
                slot_w[e * CAP + pos] = swt[base + i];
            }
            ++pos;
        }
    }
}

// ---------------- MFMA GEMM building blocks ----------------
#define WAVE_SETUP() \
    const int tid = threadIdx.x; const int lane = tid & 63; const int wid = tid >> 6; \
    const int wm = wid & 1, wn = wid >> 1; \
    const int lr16 = lane & 15, kc = lane >> 4; \
    const int kq = tid & 7; const int rbase = tid >> 3;

#define DECL_ACC() f32x4 acc[4][4]; \
    _Pragma("unroll") for (int i_ = 0; i_ < 4; ++i_) \
    _Pragma("unroll") for (int j_ = 0; j_ < 4; ++j_) acc[i_][j_] = 0.f;

#define STAGE_F32(dstoff, src, valid) do { \
    float4 v_ = (valid) ? *(const float4*)(src) : make_float4(0.f,0.f,0.f,0.f); \
    short4v sv_; sv_.x = f2bf(v_.x); sv_.y = f2bf(v_.y); sv_.z = f2bf(v_.z); sv_.w = f2bf(v_.w); \
    *(short4v*)(dstoff) = sv_; } while (0)

#define COMPUTE32() do { \
    short8v a_[4], b_[4]; \
    _Pragma("unroll") for (int mt = 0; mt < 4; ++mt) \
        a_[mt] = *(const short8v*)&As[(wm*64 + mt*16 + lr16)*LDSTRIDE + kc*8]; \
    _Pragma("unroll") for (int nt = 0; nt < 4; ++nt) \
        b_[nt] = *(const short8v*)&Bs[(wn*64 + nt*16 + lr16)*LDSTRIDE + kc*8]; \
    _Pragma("unroll") for (int mt = 0; mt < 4; ++mt) \
    _Pragma("unroll") for (int nt = 0; nt < 4; ++nt) \
        acc[mt][nt] = __builtin_amdgcn_mfma_f32_16x16x32_bf16(a_[mt], b_[nt], acc[mt][nt], 0, 0, 0); \
} while (0)

// routed gate_up + SiLU*mul (+slot_w), bf16 act out.  grid (I/64, CAP/128, E)
__global__ __launch_bounds__(256) void moe_gu_kernel(
    const float* __restrict__ x, const float* __restrict__ w_gate_up,
    const int* __restrict__ cnt, const int* __restrict__ slot_token,
    const float* __restrict__ slot_w, short* __restrict__ act)
{
    const int e = blockIdx.z;
    const int ne = min(cnt[e], CAP);
    const int r0 = blockIdx.y * 128;
    if (r0 >= ne) return;
    const int nI0 = blockIdx.x * 64;

    __shared__ __align__(16) short As[128 * LDSTRIDE];
    __shared__ __align__(16) short Bs[128 * LDSTRIDE];
    __shared__ int   toks[128];
    __shared__ float sws[128];

    WAVE_SETUP();
    if (tid < 128) {
        int p = r0 + tid;
        toks[tid] = (p < ne) ? slot_token[e * CAP + p] : 0;
        sws[tid]  = (p < ne) ? slot_w[e * CAP + p] : 0.f;
    }
    __syncthreads();

    const float* aptr[4]; bool aval[4]; int aoff[4];
    const float* bptr[4]; int boff[4];
    const float* wgu_e = w_gate_up + (size_t)e * (2 * I_DIM) * H_DIM;
    #pragma unroll
    for (int i = 0; i < 4; ++i) {
        int r = rbase + i * 32;
        aval[i] = (r0 + r) < ne;
        aptr[i] = x + (size_t)toks[r] * H_DIM + kq * 4;
        aoff[i] = r * LDSTRIDE + kq * 4;
        int c = r;
        int wrow = ((c >> 4) & 1) * I_DIM + nI0 + (c >> 5) * 16 + (c & 15);
        bptr[i] = wgu_e + (size_t)wrow * H_DIM + kq * 4;
        boff[i] = aoff[i];
    }

    DECL_ACC();
    for (int k0 = 0; k0 < H_DIM; k0 += 32) {
        #pragma unroll
        for (int i = 0; i < 4; ++i) STAGE_F32(&As[aoff[i]], aptr[i] + k0, aval[i]);
        #pragma unroll
        for (int i = 0; i < 4; ++i) STAGE_F32(&Bs[boff[i]], bptr[i] + k0, true);
        __syncthreads();
        COMPUTE32();
        __syncthreads();
    }

    #pragma unroll
    for (int mt = 0; mt < 4; ++mt) {
        #pragma unroll
        for (int q = 0; q < 2; ++q) {
            f32x4 g = acc[mt][2 * q], u = acc[mt][2 * q + 1];
            int colI = nI0 + (wn * 2 + q) * 16 + lr16;
            #pragma unroll
            for (int i = 0; i < 4; ++i) {
                int rl = wm * 64 + mt * 16 + kc * 4 + i;
                int p = r0 + rl;
                if (p < ne) {
                    float s = sws[rl];
                    float v = s * silu_(g[i]) * u[i];
                    act[((size_t)e * CAP + p) * I_DIM + colI] = f2bf(v);
                }
            }
        }
    }
}

// routed down + scatter-add.  grid (H/128, CAP/128, E)
__global__ __launch_bounds__(256) void moe_down_kernel(
    const short* __restrict__ act, const float* __restrict__ w_down,
    const int* __restrict__ cnt, const int* __restrict__ slot_token,
    float* __restrict__ out)
{
    const int e = blockIdx.z;
    const int ne = min(cnt[e], CAP);
    const int r0 = blockIdx.y * 128;
    if (r0 >= ne) return;
    const int h0 = blockIdx.x * 128;

    __shared__ __align__(16) short As[128 * LDSTRIDE];
    __shared__ __align__(16) short Bs[128 * LDSTRIDE];
    __shared__ int toks[128];

    WAVE_SETUP();
    if (tid < 128) {
        int p = r0 + tid;
        toks[tid] = (p < ne) ? slot_token[e * CAP + p] : 0;
    }
    __syncthreads();

    const short* aptr[4]; bool aval[4]; int aoff[4];
    const float* bptr[4];
    const float* wd_e = w_down + (size_t)e * H_DIM * I_DIM;
    #pragma unroll
    for (int i = 0; i < 4; ++i) {
        int r = rbase + i * 32;
        aval[i] = (r0 + r) < ne;
        aptr[i] = act + ((size_t)e * CAP + r0 + r) * I_DIM + kq * 4;
        aoff[i] = r * LDSTRIDE + kq * 4;
        bptr[i] = wd_e + (size_t)(h0 + r) * I_DIM + kq * 4;
    }

    DECL_ACC();
    for (int k0 = 0; k0 < I_DIM; k0 += 32) {
        #pragma unroll
        for (int i = 0; i < 4; ++i) {
            short4v sv = aval[i] ? *(const short4v*)(aptr[i] + k0) : (short4v)(short)0;
            *(short4v*)&As[aoff[i]] = sv;
        }
        #pragma unroll
        for (int i = 0; i < 4; ++i) STAGE_F32(&Bs[aoff[i]], bptr[i] + k0, true);
        __syncthreads();
        COMPUTE32();
        __syncthreads();
    }

    #pragma unroll
    for (int mt = 0; mt < 4; ++mt) {
        #pragma unroll
        for (int i = 0; i < 4; ++i) {
            int rl = wm * 64 + mt * 16 + kc * 4 + i;
            int p = r0 + rl;
            if (p < ne) {
                int tt = toks[rl];
                float* orow = out + (size_t)tt * H_DIM + h0 + wn * 64;
                #pragma unroll
                for (int nt = 0; nt < 4; ++nt)
                    atomicAdd(&orow[nt * 16 + lr16], acc[mt][nt][i]);
            }
        }
    }
}

// shared-expert gate_up + SiLU*mul, bf16 acts out.  grid (IS/64, T/128)
__global__ __launch_bounds__(256) void shared_gu_kernel(
    const float* __restrict__ x, const float* __restrict__ w_gus,
    short* __restrict__ acts)
{
    const int t0 = blockIdx.y * 128;
    const int nI0 = blockIdx.x * 64;
    __shared__ __align__(16) short As[128 * LDSTRIDE];
    __shared__ __align__(16) short Bs[128 * LDSTRIDE];

    WAVE_SETUP();
    const float* aptr[4]; const float* bptr[4]; int aoff[4];
    #pragma unroll
    for (int i = 0; i < 4; ++i) {
        int r = rbase + i * 32;
        aptr[i] = x + (size_t)(t0 + r) * H_DIM + kq * 4;
        aoff[i] = r * LDSTRIDE + kq * 4;
        int c = r;
        int wrow = ((c >> 4) & 1) * IS_DIM + nI0 + (c >> 5) * 16 + (c & 15);
        bptr[i] = w_gus + (size_t)wrow * H_DIM + kq * 4;
    }

    DECL_ACC();
    for (int k0 = 0; k0 < H_DIM; k0 += 32) {
        #pragma unroll
        for (int i = 0; i < 4; ++i) STAGE_F32(&As[aoff[i]], aptr[i] + k0, true);
        #pragma unroll
        for (int i = 0; i < 4; ++i) STAGE_F32(&Bs[aoff[i]], bptr[i] + k0, true);
        __syncthreads();
        COMPUTE32();
        __syncthreads();
    }

    #pragma unroll
    for (int mt = 0; mt < 4; ++mt) {
        #pragma unroll
        for (int q = 0; q < 2; ++q) {
            f32x4 g = acc[mt][2 * q], u = acc[mt][2 * q + 1];
            int colI = nI0 + (wn * 2 + q) * 16 + lr16;
            #pragma unroll
            for (int i = 0; i < 4; ++i) {
                int t = t0 + wm * 64 + mt * 16 + kc * 4 + i;
                acts[(size_t)t * IS_DIM + colI] = f2bf(silu_(g[i]) * u[i]);
            }
        }
    }
}

// shared-expert down, plain write (initializes out).  grid (H/128, T/128)
__global__ __launch_bounds__(256) void shared_down_kernel(
    const short* __restrict__ acts, const float* __restrict__ w_ds,
    float* __restrict__ out)
{
    const int t0 = blockIdx.y * 128;
    const int h0 = blockIdx.x * 128;
    __shared__ __align__(16) short As[128 * LDSTRIDE];
    __shared__ __align__(16) short Bs[128 * LDSTRIDE];

    WAVE_SETUP();
    const short* aptr[4]; const float* bptr[4]; int aoff[4];
    #pragma unroll
    for (int i = 0; i < 4; ++i) {
        int r = rbase + i * 32;
        aptr[i] = acts + (size_t)(t0 + r) * IS_DIM + kq * 4;
        aoff[i] = r * LDSTRIDE + kq * 4;
        bptr[i] = w_ds + (size_t)(h0 + r) * IS_DIM + kq * 4;
    }

    DECL_ACC();
    for (int k0 = 0; k0 < IS_DIM; k0 += 32) {
        #pragma unroll
        for (int i = 0; i < 4; ++i) {
            short4v sv = *(const short4v*)(aptr[i] + k0);
            *(short4v*)&As[aoff[i]] = sv;
        }
        #pragma unroll
        for (int i = 0; i < 4; ++i) STAGE_F32(&Bs[aoff[i]], bptr[i] + k0, true);
        __syncthreads();
        COMPUTE32();
        __syncthreads();
    }

    #pragma unroll
    for (int mt = 0; mt < 4; ++mt) {
        #pragma unroll
        for (int i = 0; i < 4; ++i) {
            int t = t0 + wm * 64 + mt * 16 + kc * 4 + i;
            float* orow = out + (size_t)t * H_DIM + h0 + wn * 64;
            #pragma unroll
            for (int nt = 0; nt < 4; ++nt)
                orow[nt * 16 + lr16] = acc[mt][nt][i];
        }
    }
}

extern "C" void kernel_launch(void* const* d_in, const int* in_sizes, int n_in,
                              void* d_out, int out_size, void* d_ws, size_t ws_size,
                              hipStream_t stream) {
    const float* x   = (const float*)d_in[0];
    const float* gw  = (const float*)d_in[1];
    const float* eb  = (const float*)d_in[2];
    const float* wgu = (const float*)d_in[3];
    const float* wd  = (const float*)d_in[4];
    const float* wgs = (const float*)d_in[5];
    const float* wds = (const float*)d_in[6];
    float* out = (float*)d_out;
    char* ws = (char*)d_ws;

    int*   cnt   = (int*)(ws + 0);
    int*   eidx  = (int*)(ws + WS_EIDX_OFF);
    float* wnorm = (float*)(ws + WS_WN_OFF);
    int*   stok  = (int*)(ws + WS_STOK_OFF);
    float* sw    = (float*)(ws + WS_SW_OFF);
    short* act   = (short*)(ws + WS_ACT_OFF);
    short* acts  = (short*)(ws + WS_ACTS_OFF);

    gate_kernel<<<T_TOK, 256, 0, stream>>>(x, gw, eb, eidx, wnorm);
    assign_kernel<<<1, 256, 0, stream>>>(eidx, wnorm, cnt, stok, sw);
    shared_gu_kernel<<<dim3(IS_DIM / 64, T_TOK / 128), 256, 0, stream>>>(x, wgs, acts);
    shared_down_kernel<<<dim3(H_DIM / 128, T_TOK / 128), 256, 0, stream>>>(acts, wds, out);
    moe_gu_kernel<<<dim3(I_DIM / 64, CAP / 128, E_NUM), 256, 0, stream>>>(x, wgu, cnt, stok, sw, act);
    moe_down_kernel<<<dim3(H_DIM / 128, CAP / 128, E_NUM), 256, 0, stream>>>(act, wd, cnt, stok, out);
}

// Round 4
// 431.992 us; speedup vs baseline: 1.5947x; 1.1393x over previous
//
#include <hip/hip_runtime.h>
#include <hip/hip_bf16.h>
#include <math.h>

// Problem constants (match reference)
#define T_TOK 1024
#define H_DIM 1024
#define I_DIM 512
#define E_NUM 32
#define K_TOP 4
#define G_NUM 8
#define TG_NUM 4
#define CAP 256              // C = 2*T*K/E
#define IS_DIM 1024          // I * NS
#define RSCALE 2.5f

// ws layout (byte offsets)
#define WS_CNT_OFF    0          // int cnt[32]
#define WS_NT_OFF     128        // int ntiles
#define WS_TILE_OFF   256        // int tiles[128][4] = (e, r0, ne, pad)
#define WS_EIDX_OFF   4096       // int eidx[T*K]
#define WS_WN_OFF     20480      // float wnorm[T*K]
#define WS_STOK_OFF   36864      // int slot_token[E*CAP]
#define WS_SW_OFF     69632     // float slot_w[E*CAP]
#define WS_ACT_OFF    102400     // bf16 act[E*CAP*I]  (8 MB)
#define WS_ACTS_OFF   (102400 + (size_t)E_NUM*CAP*I_DIM*2)  // bf16 acts[T*IS] (2 MB)

typedef __attribute__((ext_vector_type(8))) short short8v;
typedef __attribute__((ext_vector_type(4))) float f32x4;
typedef __attribute__((ext_vector_type(4))) unsigned uint4v;

__device__ __forceinline__ short f2bf(float f) {          // RNE, epilogue only
    unsigned u = __float_as_uint(f);
    u += 0x7FFFu + ((u >> 16) & 1u);
    return (short)(u >> 16);
}
// pack 2 floats -> 2 bf16 (round-half-up): 3 VALU ops
__device__ __forceinline__ unsigned pk2bf(float a, float b) {
    unsigned ua = __float_as_uint(a) + 0x8000u;
    unsigned ub = __float_as_uint(b) + 0x8000u;
    return __builtin_amdgcn_perm(ub, ua, 0x07060302);      // lo short=bf(a), hi=bf(b)
}
__device__ __forceinline__ uint4v pk8bf(float4 lo, float4 hi) {
    uint4v r; r.x = pk2bf(lo.x, lo.y); r.y = pk2bf(lo.z, lo.w);
    r.z = pk2bf(hi.x, hi.y); r.w = pk2bf(hi.z, hi.w); return r;
}
__device__ __forceinline__ float silu_(float g) { return g / (1.f + expf(-g)); }

#define LDSTRIDE 40   // shorts per LDS row (80 B, keeps b128 writes aligned)

// -------- gating --------
__global__ __launch_bounds__(256) void gate_kernel(
    const float* __restrict__ x, const float* __restrict__ gate_w,
    const float* __restrict__ e_bias,
    int* __restrict__ eidx, float* __restrict__ wnorm)
{
    __shared__ float xs[H_DIM];
    __shared__ float logits[E_NUM];
    const int t = blockIdx.x;
    const int tid = threadIdx.x;
    ((float4*)xs)[tid] = ((const float4*)(x + (size_t)t * H_DIM))[tid];
    __syncthreads();

    const int e = tid >> 3, sub = tid & 7;   // 32 experts x 8 threads
    const float4* gw4 = (const float4*)(gate_w + (size_t)e * H_DIM + sub * 128);
    const float4* xr4 = (const float4*)(xs + sub * 128);
    float p = 0.f;
    #pragma unroll
    for (int h = 0; h < 32; ++h) {
        float4 a = xr4[h], b = gw4[h];
        p += a.x * b.x + a.y * b.y + a.z * b.z + a.w * b.w;
    }
    for (int off = 4; off; off >>= 1) p += __shfl_down(p, off, 8);
    if (sub == 0) logits[e] = p;
    __syncthreads();
    if (tid != 0) return;

    float sc[E_NUM], sfc[E_NUM];
    for (int i = 0; i < E_NUM; ++i) {
        sc[i] = 1.f / (1.f + expf(-logits[i]));
        sfc[i] = sc[i] + e_bias[i];
    }
    float gs[G_NUM];
    for (int g = 0; g < G_NUM; ++g) {
        float m1 = -1e30f, m2 = -1e30f;
        for (int j = 0; j < E_NUM / G_NUM; ++j) {
            float v = sfc[g * (E_NUM / G_NUM) + j];
            if (v > m1) { m2 = m1; m1 = v; } else if (v > m2) m2 = v;
        }
        gs[g] = m1 + m2;
    }
    bool gm[G_NUM];
    for (int g = 0; g < G_NUM; ++g) gm[g] = false;
    for (int it = 0; it < TG_NUM; ++it) {
        int best = -1; float bv = -1e30f;
        for (int g = 0; g < G_NUM; ++g) if (!gm[g] && gs[g] > bv) { bv = gs[g]; best = g; }
        gm[best] = true;
    }
    float sm[E_NUM];
    for (int i = 0; i < E_NUM; ++i) sm[i] = gm[i / (E_NUM / G_NUM)] ? sfc[i] : 0.0f;
    int idx[K_TOP]; float w[K_TOP]; float tsum = 0.f;
    for (int it = 0; it < K_TOP; ++it) {
        int best = 0; float bv = -1e30f;
        for (int i = 0; i < E_NUM; ++i) if (sm[i] > bv) { bv = sm[i]; best = i; }
        sm[best] = -1e30f;
        idx[it] = best; w[it] = sc[best]; tsum += w[it];
    }
    float inv = RSCALE / (tsum + 1e-20f);
    const int base = t * K_TOP;
    for (int it = 0; it < K_TOP; ++it) {
        eidx[base + it] = idx[it];
        wnorm[base + it] = w[it] * inv;
    }
}

// -------- deterministic capacity dispatch + tile-list build --------
__global__ __launch_bounds__(256) void assign_kernel(
    const int* __restrict__ eidx, const float* __restrict__ wnorm,
    int* __restrict__ cnt, int* __restrict__ slot_token, float* __restrict__ slot_w,
    int* __restrict__ ntiles, int* __restrict__ tiles)
{
    __shared__ int   se[T_TOK * K_TOP];
    __shared__ float swt[T_TOK * K_TOP];
    __shared__ int   scnt[E_NUM];
    const int tid = threadIdx.x;
    for (int i = tid; i < T_TOK * K_TOP; i += 256) { se[i] = eidx[i]; swt[i] = wnorm[i]; }
    __syncthreads();

    const int e = tid >> 3;
    const int seg = tid & 7;
    const int base = seg * 512;
    int c = 0;
    for (int i = 0; i < 512; ++i) c += (se[base + i] == e);
    int excl = 0, total = 0;
    for (int s = 0; s < 8; ++s) {
        int cs = __shfl(c, s, 8);
        total += cs;
        if (s < seg) excl += cs;
    }
    if (seg == 0) { cnt[e] = total; scnt[e] = total; }
    int pos = excl;
    for (int i = 0; i < 512; ++i) {
        if (se[base + i] == e) {
            if (pos < CAP) {
                slot_token[e * CAP + pos] = (base + i) >> 2;
                slot_w[e * CAP + pos] = swt[base + i];
            }
            ++pos;
        }
    }
    __syncthreads();
    if (tid == 0) {
        int nt = 0;
        for (int ee = 0; ee < E_NUM; ++ee) {
            int n = min(scnt[ee], CAP);
            for (int r = 0; r < n; r += 64) {
                tiles[nt * 4] = ee; tiles[nt * 4 + 1] = r; tiles[nt * 4 + 2] = n;
                ++nt;
            }
        }
        *ntiles = nt;
    }
}

// ---------------- MFMA GEMM: block tile 64(M) x 128(B-rows), BK=32 ----------------
#define WAVE_SETUP() \
    const int tid = threadIdx.x; const int lane = tid & 63; const int wid = tid >> 6; \
    const int wm = wid & 1, wn = wid >> 1; \
    const int lr16 = lane & 15, kc = lane >> 4; \
    const int sc_ = tid & 3, srow = tid >> 2;   /* staging: 8-elem chunk, row 0..63 */

#define DECL_ACC() f32x4 acc[2][4]; \
    _Pragma("unroll") for (int i_ = 0; i_ < 2; ++i_) \
    _Pragma("unroll") for (int j_ = 0; j_ < 4; ++j_) acc[i_][j_] = 0.f;

#define COMPUTE_2x4() do { \
    short8v a_[2], b_[4]; \
    _Pragma("unroll") for (int mt = 0; mt < 2; ++mt) \
        a_[mt] = *(const short8v*)&As[(wm*32 + mt*16 + lr16)*LDSTRIDE + kc*8]; \
    _Pragma("unroll") for (int nt = 0; nt < 4; ++nt) \
        b_[nt] = *(const short8v*)&Bs[(wn*64 + nt*16 + lr16)*LDSTRIDE + kc*8]; \
    _Pragma("unroll") for (int mt = 0; mt < 2; ++mt) \
    _Pragma("unroll") for (int nt = 0; nt < 4; ++nt) \
        acc[mt][nt] = __builtin_amdgcn_mfma_f32_16x16x32_bf16(a_[mt], b_[nt], acc[mt][nt], 0, 0, 0); \
} while (0)

// routed gate_up + SiLU*mul (+slot_w), bf16 act out.  grid (I/64, 128)
__global__ __launch_bounds__(256, 4) void moe_gu_kernel(
    const float* __restrict__ x, const float* __restrict__ w_gate_up,
    const int* __restrict__ ntiles, const int* __restrict__ tiles,
    const int* __restrict__ slot_token, const float* __restrict__ slot_w,
    short* __restrict__ act)
{
    if ((int)blockIdx.y >= *ntiles) return;
    const int e  = tiles[blockIdx.y * 4];
    const int r0 = tiles[blockIdx.y * 4 + 1];
    const int ne = tiles[blockIdx.y * 4 + 2];
    const int nI0 = blockIdx.x * 64;

    __shared__ __align__(16) short As[64 * LDSTRIDE];
    __shared__ __align__(16) short Bs[128 * LDSTRIDE];
    __shared__ int   toks[64];
    __shared__ float sws[64];

    WAVE_SETUP();
    if (tid < 64) {
        int p = r0 + tid; bool v = p < ne;
        toks[tid] = v ? slot_token[e * CAP + p] : 0;
        sws[tid]  = v ? slot_w[e * CAP + p] : 0.f;
    }
    __syncthreads();

    const float* aptr = x + (size_t)toks[srow] * H_DIM + sc_ * 8;
    const float* wgu_e = w_gate_up + (size_t)e * (2 * I_DIM) * H_DIM;
    const int cB1 = srow + 64;
    const int wr0 = ((srow >> 4) & 1) * I_DIM + nI0 + ((srow >> 5) << 4) + (srow & 15);
    const int wr1 = ((cB1 >> 4) & 1) * I_DIM + nI0 + ((cB1 >> 5) << 4) + (cB1 & 15);
    const float* bptr0 = wgu_e + (size_t)wr0 * H_DIM + sc_ * 8;
    const float* bptr1 = wgu_e + (size_t)wr1 * H_DIM + sc_ * 8;
    const int aoff = srow * LDSTRIDE + sc_ * 8;
    const int boff0 = srow * LDSTRIDE + sc_ * 8;
    const int boff1 = cB1 * LDSTRIDE + sc_ * 8;

    DECL_ACC();
    float4 cA0 = *(const float4*)(aptr), cA1 = *(const float4*)(aptr + 4);
    float4 cB0a = *(const float4*)(bptr0), cB0b = *(const float4*)(bptr0 + 4);
    float4 cB1a = *(const float4*)(bptr1), cB1b = *(const float4*)(bptr1 + 4);

    for (int k0 = 0; k0 < H_DIM; k0 += 32) {
        float4 nA0, nA1, nB0a, nB0b, nB1a, nB1b;
        const int k1 = k0 + 32;
        if (k1 < H_DIM) {
            nA0 = *(const float4*)(aptr + k1);  nA1 = *(const float4*)(aptr + k1 + 4);
            nB0a = *(const float4*)(bptr0 + k1); nB0b = *(const float4*)(bptr0 + k1 + 4);
            nB1a = *(const float4*)(bptr1 + k1); nB1b = *(const float4*)(bptr1 + k1 + 4);
        }
        *(uint4v*)&As[aoff]  = pk8bf(cA0, cA1);
        *(uint4v*)&Bs[boff0] = pk8bf(cB0a, cB0b);
        *(uint4v*)&Bs[boff1] = pk8bf(cB1a, cB1b);
        __syncthreads();
        COMPUTE_2x4();
        __syncthreads();
        cA0 = nA0; cA1 = nA1; cB0a = nB0a; cB0b = nB0b; cB1a = nB1a; cB1b = nB1b;
    }

    #pragma unroll
    for (int mt = 0; mt < 2; ++mt) {
        #pragma unroll
        for (int q = 0; q < 2; ++q) {
            f32x4 g = acc[mt][2 * q], u = acc[mt][2 * q + 1];
            int colI = nI0 + wn * 32 + q * 16 + lr16;
            #pragma unroll
            for (int i = 0; i < 4; ++i) {
                int rl = wm * 32 + mt * 16 + kc * 4 + i;
                int p = r0 + rl;
                if (p < ne) {
                    float s = sws[rl];
                    act[((size_t)e * CAP + p) * I_DIM + colI] = f2bf(s * silu_(g[i]) * u[i]);
                }
            }
        }
    }
}

// routed down + scatter-add.  grid (H/128, 128)
__global__ __launch_bounds__(256, 4) void moe_down_kernel(
    const short* __restrict__ act, const float* __restrict__ w_down,
    const int* __restrict__ ntiles, const int* __restrict__ tiles,
    const int* __restrict__ slot_token, float* __restrict__ out)
{
    if ((int)blockIdx.y >= *ntiles) return;
    const int e  = tiles[blockIdx.y * 4];
    const int r0 = tiles[blockIdx.y * 4 + 1];
    const int ne = tiles[blockIdx.y * 4 + 2];
    const int h0 = blockIdx.x * 128;

    __shared__ __align__(16) short As[64 * LDSTRIDE];
    __shared__ __align__(16) short Bs[128 * LDSTRIDE];
    __shared__ int toks[64];

    WAVE_SETUP();
    if (tid < 64) {
        int p = r0 + tid;
        toks[tid] = (p < ne) ? slot_token[e * CAP + p] : 0;
    }
    __syncthreads();

    const short* aptr = act + ((size_t)e * CAP + r0 + srow) * I_DIM + sc_ * 8;
    const float* wd_e = w_down + (size_t)e * H_DIM * I_DIM;
    const float* bptr0 = wd_e + (size_t)(h0 + srow) * I_DIM + sc_ * 8;
    const float* bptr1 = wd_e + (size_t)(h0 + srow + 64) * I_DIM + sc_ * 8;
    const int aoff = srow * LDSTRIDE + sc_ * 8;
    const int boff1 = (srow + 64) * LDSTRIDE + sc_ * 8;

    DECL_ACC();
    short8v cA = *(const short8v*)(aptr);
    float4 cB0a = *(const float4*)(bptr0), cB0b = *(const float4*)(bptr0 + 4);
    float4 cB1a = *(const float4*)(bptr1), cB1b = *(const float4*)(bptr1 + 4);

    for (int k0 = 0; k0 < I_DIM; k0 += 32) {
        short8v nA; float4 nB0a, nB0b, nB1a, nB1b;
        const int k1 = k0 + 32;
        if (k1 < I_DIM) {
            nA = *(const short8v*)(aptr + k1);
            nB0a = *(const float4*)(bptr0 + k1); nB0b = *(const float4*)(bptr0 + k1 + 4);
            nB1a = *(const float4*)(bptr1 + k1); nB1b = *(const float4*)(bptr1 + k1 + 4);
        }
        *(short8v*)&As[aoff] = cA;
        *(uint4v*)&Bs[aoff]  = pk8bf(cB0a, cB0b);
        *(uint4v*)&Bs[boff1] = pk8bf(cB1a, cB1b);
        __syncthreads();
        COMPUTE_2x4();
        __syncthreads();
        cA = nA; cB0a = nB0a; cB0b = nB0b; cB1a = nB1a; cB1b = nB1b;
    }

    #pragma unroll
    for (int mt = 0; mt < 2; ++mt) {
        #pragma unroll
        for (int i = 0; i < 4; ++i) {
            int rl = wm * 32 + mt * 16 + kc * 4 + i;
            int p = r0 + rl;
            if (p < ne) {
                float* orow = out + (size_t)toks[rl] * H_DIM + h0 + wn * 64;
                #pragma unroll
                for (int nt = 0; nt < 4; ++nt)
                    atomicAdd(&orow[nt * 16 + lr16], acc[mt][nt][i]);
            }
        }
    }
}

// shared-expert gate_up + SiLU*mul, bf16 acts out.  grid (IS/64, T/64)
__global__ __launch_bounds__(256, 4) void shared_gu_kernel(
    const float* __restrict__ x, const float* __restrict__ w_gus,
    short* __restrict__ acts)
{
    const int t0 = blockIdx.y * 64;
    const int nI0 = blockIdx.x * 64;
    __shared__ __align__(16) short As[64 * LDSTRIDE];
    __shared__ __align__(16) short Bs[128 * LDSTRIDE];

    WAVE_SETUP();
    const float* aptr = x + (size_t)(t0 + srow) * H_DIM + sc_ * 8;
    const int cB1 = srow + 64;
    const int wr0 = ((srow >> 4) & 1) * IS_DIM + nI0 + ((srow >> 5) << 4) + (srow & 15);
    const int wr1 = ((cB1 >> 4) & 1) * IS_DIM + nI0 + ((cB1 >> 5) << 4) + (cB1 & 15);
    const float* bptr0 = w_gus + (size_t)wr0 * H_DIM + sc_ * 8;
    const float* bptr1 = w_gus + (size_t)wr1 * H_DIM + sc_ * 8;
    const int aoff = srow * LDSTRIDE + sc_ * 8;
    const int boff1 = cB1 * LDSTRIDE + sc_ * 8;

    DECL_ACC();
    float4 cA0 = *(const float4*)(aptr), cA1 = *(const float4*)(aptr + 4);
    float4 cB0a = *(const float4*)(bptr0), cB0b = *(const float4*)(bptr0 + 4);
    float4 cB1a = *(const float4*)(bptr1), cB1b = *(const float4*)(bptr1 + 4);

    for (int k0 = 0; k0 < H_DIM; k0 += 32) {
        float4 nA0, nA1, nB0a, nB0b, nB1a, nB1b;
        const int k1 = k0 + 32;
        if (k1 < H_DIM) {
            nA0 = *(const float4*)(aptr + k1);  nA1 = *(const float4*)(aptr + k1 + 4);
            nB0a = *(const float4*)(bptr0 + k1); nB0b = *(const float4*)(bptr0 + k1 + 4);
            nB1a = *(const float4*)(bptr1 + k1); nB1b = *(const float4*)(bptr1 + k1 + 4);
        }
        *(uint4v*)&As[aoff]  = pk8bf(cA0, cA1);
        *(uint4v*)&Bs[aoff]  = pk8bf(cB0a, cB0b);
        *(uint4v*)&Bs[boff1] = pk8bf(cB1a, cB1b);
        __syncthreads();
        COMPUTE_2x4();
        __syncthreads();
        cA0 = nA0; cA1 = nA1; cB0a = nB0a; cB0b = nB0b; cB1a = nB1a; cB1b = nB1b;
    }

    #pragma unroll
    for (int mt = 0; mt < 2; ++mt) {
        #pragma unroll
        for (int q = 0; q < 2; ++q) {
            f32x4 g = acc[mt][2 * q], u = acc[mt][2 * q + 1];
            int colI = nI0 + wn * 32 + q * 16 + lr16;
            #pragma unroll
            for (int i = 0; i < 4; ++i) {
                int t = t0 + wm * 32 + mt * 16 + kc * 4 + i;
                acts[(size_t)t * IS_DIM + colI] = f2bf(silu_(g[i]) * u[i]);
            }
        }
    }
}

// shared-expert down, plain write (initializes out).  grid (H/128, T/64)
__global__ __launch_bounds__(256, 4) void shared_down_kernel(
    const short* __restrict__ acts, const float* __restrict__ w_ds,
    float* __restrict__ out)
{
    const int t0 = blockIdx.y * 64;
    const int h0 = blockIdx.x * 128;
    __shared__ __align__(16) short As[64 * LDSTRIDE];
    __shared__ __align__(16) short Bs[128 * LDSTRIDE];

    WAVE_SETUP();
    const short* aptr = acts + (size_t)(t0 + srow) * IS_DIM + sc_ * 8;
    const float* bptr0 = w_ds + (size_t)(h0 + srow) * IS_DIM + sc_ * 8;
    const float* bptr1 = w_ds + (size_t)(h0 + srow + 64) * IS_DIM + sc_ * 8;
    const int aoff = srow * LDSTRIDE + sc_ * 8;
    const int boff1 = (srow + 64) * LDSTRIDE + sc_ * 8;

    DECL_ACC();
    short8v cA = *(const short8v*)(aptr);
    float4 cB0a = *(const float4*)(bptr0), cB0b = *(const float4*)(bptr0 + 4);
    float4 cB1a = *(const float4*)(bptr1), cB1b = *(const float4*)(bptr1 + 4);

    for (int k0 = 0; k0 < IS_DIM; k0 += 32) {
        short8v nA; float4 nB0a, nB0b, nB1a, nB1b;
        const int k1 = k0 + 32;
        if (k1 < IS_DIM) {
            nA = *(const short8v*)(aptr + k1);
            nB0a = *(const float4*)(bptr0 + k1); nB0b = *(const float4*)(bptr0 + k1 + 4);
            nB1a = *(const float4*)(bptr1 + k1); nB1b = *(const float4*)(bptr1 + k1 + 4);
        }
        *(short8v*)&As[aoff] = cA;
        *(uint4v*)&Bs[aoff]  = pk8bf(cB0a, cB0b);
        *(uint4v*)&Bs[boff1] = pk8bf(cB1a, cB1b);
        __syncthreads();
        COMPUTE_2x4();
        __syncthreads();
        cA = nA; cB0a = nB0a; cB0b = nB0b; cB1a = nB1a; cB1b = nB1b;
    }

    #pragma unroll
    for (int mt = 0; mt < 2; ++mt) {
        #pragma unroll
        for (int i = 0; i < 4; ++i) {
            int t = t0 + wm * 32 + mt * 16 + kc * 4 + i;
            float* orow = out + (size_t)t * H_DIM + h0 + wn * 64;
            #pragma unroll
            for (int nt = 0; nt < 4; ++nt)
                orow[nt * 16 + lr16] = acc[mt][nt][i];
        }
    }
}

extern "C" void kernel_launch(void* const* d_in, const int* in_sizes, int n_in,
                              void* d_out, int out_size, void* d_ws, size_t ws_size,
                              hipStream_t stream) {
    const float* x   = (const float*)d_in[0];
    const float* gw  = (const float*)d_in[1];
    const float* eb  = (const float*)d_in[2];
    const float* wgu = (const float*)d_in[3];
    const float* wd  = (const float*)d_in[4];
    const float* wgs = (const float*)d_in[5];
    const float* wds = (const float*)d_in[6];
    float* out = (float*)d_out;
    char* ws = (char*)d_ws;

    int*   cnt    = (int*)(ws + WS_CNT_OFF);
    int*   ntiles = (int*)(ws + WS_NT_OFF);
    int*   tiles  = (int*)(ws + WS_TILE_OFF);
    int*   eidx   = (int*)(ws + WS_EIDX_OFF);
    float* wnorm  = (float*)(ws + WS_WN_OFF);
    int*   stok   = (int*)(ws + WS_STOK_OFF);
    float* sw     = (float*)(ws + WS_SW_OFF);
    short* act    = (short*)(ws + WS_ACT_OFF);
    short* acts   = (short*)(ws + WS_ACTS_OFF);

    gate_kernel<<<T_TOK, 256, 0, stream>>>(x, gw, eb, eidx, wnorm);
    assign_kernel<<<1, 256, 0, stream>>>(eidx, wnorm, cnt, stok, sw, ntiles, tiles);
    shared_gu_kernel<<<dim3(IS_DIM / 64, T_TOK / 64), 256, 0, stream>>>(x, wgs, acts);
    shared_down_kernel<<<dim3(H_DIM / 128, T_TOK / 64), 256, 0, stream>>>(acts, wds, out);
    moe_gu_kernel<<<dim3(I_DIM / 64, 128), 256, 0, stream>>>(x, wgu, ntiles, tiles, stok, sw, act);
    moe_down_kernel<<<dim3(H_DIM / 128, 128), 256, 0, stream>>>(act, wd, ntiles, tiles, stok, out);
}

// Round 5
// 428.013 us; speedup vs baseline: 1.6095x; 1.0093x over previous
//
#include <hip/hip_runtime.h>
#include <hip/hip_bf16.h>
#include <math.h>

// Problem constants (match reference)
#define T_TOK 1024
#define H_DIM 1024
#define I_DIM 512
#define E_NUM 32
#define K_TOP 4
#define G_NUM 8
#define TG_NUM 4
#define CAP 256              // C = 2*T*K/E
#define IS_DIM 1024          // I * NS
#define RSCALE 2.5f

#define MAXTILES 160         // <=128 routed + 16 shared

// ws layout (byte offsets)
#define WS_CNT_OFF    0          // int cnt[32]
#define WS_NT_OFF     128        // int ntiles
#define WS_TILE_OFF   256        // int tiles[MAXTILES][4] = (e, r0, ne, pad)
#define WS_EIDX_OFF   4096       // int eidx[T*K]
#define WS_WN_OFF     20480      // float wnorm[T*K]
#define WS_STOK_OFF   36864      // int slot_token[E*CAP]
#define WS_SW_OFF     69632      // float slot_w[E*CAP]
#define WS_ACT_OFF    102400     // bf16 act[E*CAP*I]  (8 MB)
#define WS_ACTS_OFF   (102400 + (size_t)E_NUM*CAP*I_DIM*2)  // bf16 acts[T*IS] (2 MB)

typedef __attribute__((ext_vector_type(8))) short short8v;
typedef __attribute__((ext_vector_type(4))) float f32x4;
typedef __attribute__((ext_vector_type(4))) unsigned uint4v;

__device__ __forceinline__ short f2bf(float f) {          // RNE, epilogue only
    unsigned u = __float_as_uint(f);
    u += 0x7FFFu + ((u >> 16) & 1u);
    return (short)(u >> 16);
}
// pack 2 floats -> 2 bf16 (round-half-up): 3 VALU ops
__device__ __forceinline__ unsigned pk2bf(float a, float b) {
    unsigned ua = __float_as_uint(a) + 0x8000u;
    unsigned ub = __float_as_uint(b) + 0x8000u;
    return __builtin_amdgcn_perm(ub, ua, 0x07060302);      // lo short=bf(a), hi=bf(b)
}
__device__ __forceinline__ uint4v pk8bf(float4 lo, float4 hi) {
    uint4v r; r.x = pk2bf(lo.x, lo.y); r.y = pk2bf(lo.z, lo.w);
    r.z = pk2bf(hi.x, hi.y); r.w = pk2bf(hi.z, hi.w); return r;
}
__device__ __forceinline__ float silu_(float g) { return g / (1.f + expf(-g)); }

#define LDSTRIDE 40   // shorts per LDS row (80 B, keeps b128 writes aligned)

// -------- gating --------
__global__ __launch_bounds__(256) void gate_kernel(
    const float* __restrict__ x, const float* __restrict__ gate_w,
    const float* __restrict__ e_bias,
    int* __restrict__ eidx, float* __restrict__ wnorm)
{
    __shared__ float xs[H_DIM];
    __shared__ float logits[E_NUM];
    const int t = blockIdx.x;
    const int tid = threadIdx.x;
    ((float4*)xs)[tid] = ((const float4*)(x + (size_t)t * H_DIM))[tid];
    __syncthreads();

    const int e = tid >> 3, sub = tid & 7;   // 32 experts x 8 threads
    const float4* gw4 = (const float4*)(gate_w + (size_t)e * H_DIM + sub * 128);
    const float4* xr4 = (const float4*)(xs + sub * 128);
    float p = 0.f;
    #pragma unroll
    for (int h = 0; h < 32; ++h) {
        float4 a = xr4[h], b = gw4[h];
        p += a.x * b.x + a.y * b.y + a.z * b.z + a.w * b.w;
    }
    for (int off = 4; off; off >>= 1) p += __shfl_down(p, off, 8);
    if (sub == 0) logits[e] = p;
    __syncthreads();
    if (tid != 0) return;

    float sc[E_NUM], sfc[E_NUM];
    for (int i = 0; i < E_NUM; ++i) {
        sc[i] = 1.f / (1.f + expf(-logits[i]));
        sfc[i] = sc[i] + e_bias[i];
    }
    float gs[G_NUM];
    for (int g = 0; g < G_NUM; ++g) {
        float m1 = -1e30f, m2 = -1e30f;
        for (int j = 0; j < E_NUM / G_NUM; ++j) {
            float v = sfc[g * (E_NUM / G_NUM) + j];
            if (v > m1) { m2 = m1; m1 = v; } else if (v > m2) m2 = v;
        }
        gs[g] = m1 + m2;
    }
    bool gm[G_NUM];
    for (int g = 0; g < G_NUM; ++g) gm[g] = false;
    for (int it = 0; it < TG_NUM; ++it) {
        int best = -1; float bv = -1e30f;
        for (int g = 0; g < G_NUM; ++g) if (!gm[g] && gs[g] > bv) { bv = gs[g]; best = g; }
        gm[best] = true;
    }
    float sm[E_NUM];
    for (int i = 0; i < E_NUM; ++i) sm[i] = gm[i / (E_NUM / G_NUM)] ? sfc[i] : 0.0f;
    int idx[K_TOP]; float w[K_TOP]; float tsum = 0.f;
    for (int it = 0; it < K_TOP; ++it) {
        int best = 0; float bv = -1e30f;
        for (int i = 0; i < E_NUM; ++i) if (sm[i] > bv) { bv = sm[i]; best = i; }
        sm[best] = -1e30f;
        idx[it] = best; w[it] = sc[best]; tsum += w[it];
    }
    float inv = RSCALE / (tsum + 1e-20f);
    const int base = t * K_TOP;
    for (int it = 0; it < K_TOP; ++it) {
        eidx[base + it] = idx[it];
        wnorm[base + it] = w[it] * inv;
    }
}

// -------- deterministic capacity dispatch + unified tile-list build --------
__global__ __launch_bounds__(256) void assign_kernel(
    const int* __restrict__ eidx, const float* __restrict__ wnorm,
    int* __restrict__ cnt, int* __restrict__ slot_token, float* __restrict__ slot_w,
    int* __restrict__ ntiles, int* __restrict__ tiles)
{
    __shared__ int   se[T_TOK * K_TOP];
    __shared__ float swt[T_TOK * K_TOP];
    __shared__ int   scnt[E_NUM];
    const int tid = threadIdx.x;
    for (int i = tid; i < T_TOK * K_TOP; i += 256) { se[i] = eidx[i]; swt[i] = wnorm[i]; }
    __syncthreads();

    const int e = tid >> 3;
    const int seg = tid & 7;
    const int base = seg * 512;
    int c = 0;
    for (int i = 0; i < 512; ++i) c += (se[base + i] == e);
    int excl = 0, total = 0;
    for (int s = 0; s < 8; ++s) {
        int cs = __shfl(c, s, 8);
        total += cs;
        if (s < seg) excl += cs;
    }
    if (seg == 0) { cnt[e] = total; scnt[e] = total; }
    int pos = excl;
    for (int i = 0; i < 512; ++i) {
        if (se[base + i] == e) {
            if (pos < CAP) {
                slot_token[e * CAP + pos] = (base + i) >> 2;
                slot_w[e * CAP + pos] = swt[base + i];
            }
            ++pos;
        }
    }
    __syncthreads();
    if (tid == 0) {
        int nt = 0;
        // shared-expert tiles first (uniform, independent of routing)
        for (int t0 = 0; t0 < T_TOK; t0 += 64) {
            tiles[nt * 4] = -1; tiles[nt * 4 + 1] = t0; tiles[nt * 4 + 2] = 64; ++nt;
        }
        for (int ee = 0; ee < E_NUM; ++ee) {
            int n = min(scnt[ee], CAP);
            for (int r = 0; r < n; r += 64) {
                tiles[nt * 4] = ee; tiles[nt * 4 + 1] = r; tiles[nt * 4 + 2] = n; ++nt;
            }
        }
        *ntiles = nt;
    }
}

// ---------------- MFMA GEMM: block tile 64(M) x 128(B-rows), BK=32, LDS dbuf ----
#define WAVE_SETUP() \
    const int tid = threadIdx.x; const int lane = tid & 63; const int wid = tid >> 6; \
    const int wm = wid & 1, wn = wid >> 1; \
    const int lr16 = lane & 15, kc = lane >> 4; \
    const int sc_ = tid & 3, srow = tid >> 2;   /* staging: 8-elem chunk, row 0..63 */

#define DECL_ACC() f32x4 acc[2][4]; \
    _Pragma("unroll") for (int i_ = 0; i_ < 2; ++i_) \
    _Pragma("unroll") for (int j_ = 0; j_ < 4; ++j_) acc[i_][j_] = 0.f;

#define COMPUTE_2x4(Asb, Bsb) do { \
    short8v a_[2], b_[4]; \
    _Pragma("unroll") for (int mt = 0; mt < 2; ++mt) \
        a_[mt] = *(const short8v*)&(Asb)[(wm*32 + mt*16 + lr16)*LDSTRIDE + kc*8]; \
    _Pragma("unroll") for (int nt = 0; nt < 4; ++nt) \
        b_[nt] = *(const short8v*)&(Bsb)[(wn*64 + nt*16 + lr16)*LDSTRIDE + kc*8]; \
    _Pragma("unroll") for (int mt = 0; mt < 2; ++mt) \
    _Pragma("unroll") for (int nt = 0; nt < 4; ++nt) \
        acc[mt][nt] = __builtin_amdgcn_mfma_f32_16x16x32_bf16(a_[mt], b_[nt], acc[mt][nt], 0, 0, 0); \
} while (0)

// unified gate_up + SiLU*mul for routed (+slot_w) AND shared experts.
// grid (16, MAXTILES): routed tiles use x<8 (I=512), shared use all 16 (IS=1024).
__global__ __launch_bounds__(256, 4) void gu_all_kernel(
    const float* __restrict__ x, const float* __restrict__ w_gate_up,
    const float* __restrict__ w_gus,
    const int* __restrict__ ntiles, const int* __restrict__ tiles,
    const int* __restrict__ slot_token, const float* __restrict__ slot_w,
    short* __restrict__ act, short* __restrict__ acts)
{
    if ((int)blockIdx.y >= *ntiles) return;
    const int e  = tiles[blockIdx.y * 4];
    const int r0 = tiles[blockIdx.y * 4 + 1];
    const int ne = tiles[blockIdx.y * 4 + 2];
    const bool sh = (e < 0);
    if (!sh && blockIdx.x >= I_DIM / 64) return;
    const int col0 = blockIdx.x * 64;

    __shared__ __align__(16) short As[2][64 * LDSTRIDE];
    __shared__ __align__(16) short Bs[2][128 * LDSTRIDE];
    __shared__ int   toks[64];
    __shared__ float sws[64];

    WAVE_SETUP();
    if (tid < 64) {
        if (sh) { toks[tid] = r0 + tid; sws[tid] = 1.f; }
        else {
            int p = r0 + tid; bool v = p < ne;
            toks[tid] = v ? slot_token[e * CAP + p] : 0;
            sws[tid]  = v ? slot_w[e * CAP + p] : 0.f;
        }
    }
    __syncthreads();

    const int IDim = sh ? IS_DIM : I_DIM;
    const float* wbase = sh ? w_gus : (w_gate_up + (size_t)e * (2 * I_DIM) * H_DIM);
    const int c1 = srow + 64;
    const int wr0 = ((srow >> 4) & 1) * IDim + col0 + ((srow >> 5) << 4) + (srow & 15);
    const int wr1 = ((c1 >> 4) & 1) * IDim + col0 + ((c1 >> 5) << 4) + (c1 & 15);
    const float* aptr  = x + (size_t)toks[srow] * H_DIM + sc_ * 8;
    const float* bptr0 = wbase + (size_t)wr0 * H_DIM + sc_ * 8;
    const float* bptr1 = wbase + (size_t)wr1 * H_DIM + sc_ * 8;
    const int aoff  = srow * LDSTRIDE + sc_ * 8;
    const int boff1 = c1 * LDSTRIDE + sc_ * 8;

    DECL_ACC();
    float4 cA0 = *(const float4*)(aptr),  cA1 = *(const float4*)(aptr + 4);
    float4 cB0a = *(const float4*)(bptr0), cB0b = *(const float4*)(bptr0 + 4);
    float4 cB1a = *(const float4*)(bptr1), cB1b = *(const float4*)(bptr1 + 4);

    int buf = 0;
    for (int k0 = 0; k0 < H_DIM; k0 += 32) {
        float4 nA0, nA1, nB0a, nB0b, nB1a, nB1b;
        const int k1 = k0 + 32;
        if (k1 < H_DIM) {
            nA0 = *(const float4*)(aptr + k1);   nA1 = *(const float4*)(aptr + k1 + 4);
            nB0a = *(const float4*)(bptr0 + k1); nB0b = *(const float4*)(bptr0 + k1 + 4);
            nB1a = *(const float4*)(bptr1 + k1); nB1b = *(const float4*)(bptr1 + k1 + 4);
        }
        *(uint4v*)&As[buf][aoff]  = pk8bf(cA0, cA1);
        *(uint4v*)&Bs[buf][aoff]  = pk8bf(cB0a, cB0b);
        *(uint4v*)&Bs[buf][boff1] = pk8bf(cB1a, cB1b);
        __syncthreads();
        COMPUTE_2x4(As[buf], Bs[buf]);
        buf ^= 1;
        cA0 = nA0; cA1 = nA1; cB0a = nB0a; cB0b = nB0b; cB1a = nB1a; cB1b = nB1b;
    }

    short* rowbase = sh ? (acts + (size_t)r0 * IS_DIM)
                        : (act + ((size_t)e * CAP + r0) * I_DIM);
    #pragma unroll
    for (int mt = 0; mt < 2; ++mt) {
        #pragma unroll
        for (int q = 0; q < 2; ++q) {
            f32x4 g = acc[mt][2 * q], u = acc[mt][2 * q + 1];
            int colI = col0 + wn * 32 + q * 16 + lr16;
            #pragma unroll
            for (int i = 0; i < 4; ++i) {
                int rl = wm * 32 + mt * 16 + kc * 4 + i;
                if (rl < ne - r0 || sh) {
                    float s = sws[rl];
                    rowbase[(size_t)rl * IDim + colI] = f2bf(s * silu_(g[i]) * u[i]);
                }
            }
        }
    }
}

// unified down-proj + atomic scatter onto zeroed out.  grid (8, MAXTILES)
__global__ __launch_bounds__(256, 4) void down_all_kernel(
    const short* __restrict__ act, const short* __restrict__ acts,
    const float* __restrict__ w_down, const float* __restrict__ w_ds,
    const int* __restrict__ ntiles, const int* __restrict__ tiles,
    const int* __restrict__ slot_token, float* __restrict__ out)
{
    if ((int)blockIdx.y >= *ntiles) return;
    const int e  = tiles[blockIdx.y * 4];
    const int r0 = tiles[blockIdx.y * 4 + 1];
    const int ne = tiles[blockIdx.y * 4 + 2];
    const bool sh = (e < 0);
    const int h0 = blockIdx.x * 128;

    __shared__ __align__(16) short As[2][64 * LDSTRIDE];
    __shared__ __align__(16) short Bs[2][128 * LDSTRIDE];
    __shared__ int toks[64];

    WAVE_SETUP();
    if (tid < 64) {
        if (sh) toks[tid] = r0 + tid;
        else {
            int p = r0 + tid;
            toks[tid] = (p < ne) ? slot_token[e * CAP + p] : 0;
        }
    }
    __syncthreads();

    const int Kdim = sh ? IS_DIM : I_DIM;
    const short* abase = sh ? (acts + (size_t)(r0 + srow) * IS_DIM)
                            : (act + ((size_t)e * CAP + r0 + srow) * I_DIM);
    const float* wbase = sh ? w_ds : (w_down + (size_t)e * H_DIM * I_DIM);
    const float* bptr0 = wbase + (size_t)(h0 + srow) * Kdim + sc_ * 8;
    const float* bptr1 = wbase + (size_t)(h0 + srow + 64) * Kdim + sc_ * 8;
    const short* aptr  = abase + sc_ * 8;
    const int aoff  = srow * LDSTRIDE + sc_ * 8;
    const int boff1 = (srow + 64) * LDSTRIDE + sc_ * 8;

    DECL_ACC();
    short8v cA = *(const short8v*)(aptr);
    float4 cB0a = *(const float4*)(bptr0), cB0b = *(const float4*)(bptr0 + 4);
    float4 cB1a = *(const float4*)(bptr1), cB1b = *(const float4*)(bptr1 + 4);

    int buf = 0;
    for (int k0 = 0; k0 < Kdim; k0 += 32) {
        short8v nA; float4 nB0a, nB0b, nB1a, nB1b;
        const int k1 = k0 + 32;
        if (k1 < Kdim) {
            nA = *(const short8v*)(aptr + k1);
            nB0a = *(const float4*)(bptr0 + k1); nB0b = *(const float4*)(bptr0 + k1 + 4);
            nB1a = *(const float4*)(bptr1 + k1); nB1b = *(const float4*)(bptr1 + k1 + 4);
        }
        *(short8v*)&As[buf][aoff] = cA;
        *(uint4v*)&Bs[buf][aoff]  = pk8bf(cB0a, cB0b);
        *(uint4v*)&Bs[buf][boff1] = pk8bf(cB1a, cB1b);
        __syncthreads();
        COMPUTE_2x4(As[buf], Bs[buf]);
        buf ^= 1;
        cA = nA; cB0a = nB0a; cB0b = nB0b; cB1a = nB1a; cB1b = nB1b;
    }

    #pragma unroll
    for (int mt = 0; mt < 2; ++mt) {
        #pragma unroll
        for (int i = 0; i < 4; ++i) {
            int rl = wm * 32 + mt * 16 + kc * 4 + i;
            if (rl < ne - r0 || sh) {
                float* orow = out + (size_t)toks[rl] * H_DIM + h0 + wn * 64;
                #pragma unroll
                for (int nt = 0; nt < 4; ++nt)
                    atomicAdd(&orow[nt * 16 + lr16], acc[mt][nt][i]);
            }
        }
    }
}

extern "C" void kernel_launch(void* const* d_in, const int* in_sizes, int n_in,
                              void* d_out, int out_size, void* d_ws, size_t ws_size,
                              hipStream_t stream) {
    const float* x   = (const float*)d_in[0];
    const float* gw  = (const float*)d_in[1];
    const float* eb  = (const float*)d_in[2];
    const float* wgu = (const float*)d_in[3];
    const float* wd  = (const float*)d_in[4];
    const float* wgs = (const float*)d_in[5];
    const float* wds = (const float*)d_in[6];
    float* out = (float*)d_out;
    char* ws = (char*)d_ws;

    int*   cnt    = (int*)(ws + WS_CNT_OFF);
    int*   ntiles = (int*)(ws + WS_NT_OFF);
    int*   tiles  = (int*)(ws + WS_TILE_OFF);
    int*   eidx   = (int*)(ws + WS_EIDX_OFF);
    float* wnorm  = (float*)(ws + WS_WN_OFF);
    int*   stok   = (int*)(ws + WS_STOK_OFF);
    float* sw     = (float*)(ws + WS_SW_OFF);
    short* act    = (short*)(ws + WS_ACT_OFF);
    short* acts   = (short*)(ws + WS_ACTS_OFF);

    hipMemsetAsync(out, 0, (size_t)T_TOK * H_DIM * sizeof(float), stream);
    gate_kernel<<<T_TOK, 256, 0, stream>>>(x, gw, eb, eidx, wnorm);
    assign_kernel<<<1, 256, 0, stream>>>(eidx, wnorm, cnt, stok, sw, ntiles, tiles);
    gu_all_kernel<<<dim3(IS_DIM / 64, MAXTILES), 256, 0, stream>>>(
        x, wgu, wgs, ntiles, tiles, stok, sw, act, acts);
    down_all_kernel<<<dim3(H_DIM / 128, MAXTILES), 256, 0, stream>>>(
        act, acts, wd, wds, ntiles, tiles, stok, out);
}